// Round 4
// baseline (319.148 us; speedup 1.0000x reference)
//
#include <hip/hip_runtime.h>
#include <hip/hip_bf16.h>
#include <stdint.h>
#include <stddef.h>

#define NQ 384
#define NK 384

typedef __attribute__((ext_vector_type(4))) float float4_;
typedef __attribute__((ext_vector_type(8))) short short8;
typedef __attribute__((ext_vector_type(2))) unsigned int uint2_;

__device__ __forceinline__ short f2bf(float f) {
  union { float f; uint32_t u; } v; v.f = f;
  uint32_t u = v.u;
  uint32_t r = (u + 0x7fffu + ((u >> 16) & 1u)) >> 16;
  return (short)r;
}

__device__ __forceinline__ unsigned int pk2(float lo, float hi) {
  __hip_bfloat162 r = __float22bfloat162_rn(make_float2(lo, hi));
  union { __hip_bfloat162 b; unsigned int u; } u; u.b = r;
  return u.u;
}

// ---------------- prep0: weight combine + bias combine + frag pack ----------------
__global__ __launch_bounds__(256) void prep0(
    const float* __restrict__ Wq, const float* __restrict__ Wk,
    const float* __restrict__ W1, const float* __restrict__ b1,
    const float* __restrict__ bq, const float* __restrict__ bk,
    const float* __restrict__ W2,
    float* __restrict__ Wqc, float* __restrict__ Wkc,
    float* __restrict__ c1, float* __restrict__ c2,
    short* __restrict__ W1dfrag, short* __restrict__ W2frag)
{
  int bid = blockIdx.x, t = threadIdx.x;
  if (bid < 32) {
    int side = bid >> 4;
    int r0 = (bid & 15) * 16;
    const float* W = side ? Wk : Wq;
    const float* W1s = W1 + side * 64 * 128;
    float* Wc = side ? Wkc : Wqc;
    __shared__ float sW[16][64];
    for (int j = t; j < 1024; j += 256) sW[j >> 6][j & 63] = W[(r0 + (j >> 6)) * 64 + (j & 63)];
    __syncthreads();
    int c = t & 127, rg = (t >> 7) * 8;
    float acc[8] = {0.f, 0.f, 0.f, 0.f, 0.f, 0.f, 0.f, 0.f};
    for (int k = 0; k < 64; ++k) {
      float wv = W1s[k * 128 + c];
      #pragma unroll
      for (int j = 0; j < 8; ++j) acc[j] += sW[rg + j][k] * wv;
    }
    for (int j = 0; j < 8; ++j) Wc[(r0 + rg + j) * 128 + c] = acc[j];
  } else if (bid == 32) {
    if (t < 256) {
      int c = t & 127, side = t >> 7;
      const float* bias = side ? bk : bq;
      const float* W1s = W1 + side * 64 * 128;
      float acc = side ? 0.f : b1[c];
      for (int k = 0; k < 64; ++k) acc += bias[k] * W1s[k * 128 + c];
      (side ? c2 : c1)[c] = acc;
    }
  } else {
    for (int idx = t; idx < 8192; idx += 256) {
      int fi = idx >> 9;
      int l  = (idx >> 3) & 63;
      int i  = idx & 7;
      { int n = fi >> 1, s = fi & 1;
        int d = s * 32 + ((l >> 4) << 3) + i;
        int f = n * 16 + (l & 15);
        W1dfrag[idx] = f2bf(W1[(128 + d) * 128 + f]); }
      { int n2 = fi >> 2, s2 = fi & 3;
        int k = s2 * 32 + ((l >> 4) << 3) + i;
        int o = n2 * 16 + (l & 15);
        W2frag[idx] = f2bf(W2[k * 64 + o]); }
    }
  }
}

// ---------------- prep1: A1 = q_inv@Wqc + c1 ; A2 = k_inv@Wkc + c2 ----------------
__global__ __launch_bounds__(256) void prep1(
    const float* __restrict__ q_inv, const float* __restrict__ k_inv,
    const float* __restrict__ Wqc, const float* __restrict__ Wkc,
    const float* __restrict__ c1, const float* __restrict__ c2,
    float* __restrict__ A1, float* __restrict__ A2)
{
  int bid = blockIdx.x, t = threadIdx.x;
  int row0 = bid * 8;
  int side = row0 >= 1536;
  int r0 = row0 - side * 1536;
  const float* inv = (side ? k_inv : q_inv) + (size_t)r0 * 256;
  const float* Wc  = side ? Wkc : Wqc;
  const float* cc  = side ? c2 : c1;
  float* A = (side ? A2 : A1) + (size_t)r0 * 128;

  __shared__ float sI[8][256];
  for (int j = t; j < 2048; j += 256) sI[j >> 8][j & 255] = inv[j];
  __syncthreads();

  int c = t & 127, rg = (t >> 7) * 4;
  float acc[4] = {0.f, 0.f, 0.f, 0.f};
  for (int k = 0; k < 256; ++k) {
    float wv = Wc[k * 128 + c];
    #pragma unroll
    for (int j = 0; j < 4; ++j) acc[j] += sI[rg + j][k] * wv;
  }
  float cv = cc[c];
  #pragma unroll
  for (int j = 0; j < 4; ++j) A[(size_t)(rg + j) * 128 + c] = acc[j] + cv;
}

// ---------------- main fused kernel ----------------
// block = (b, 32 q, 16 k); 8 waves; wave w owns qi in {4w..4w+3}
// W1 frags register-resident; W2 frags + K-equi in LDS; h wave-private LDS.
// GEMM1': hT = W1dT(A) x DotT(B) ; GEMM2': outT = W2T(A) x hT(B)
__global__ __launch_bounds__(512, 2) void main_kernel(
    const float* __restrict__ q_equi, const float* __restrict__ k_equi,
    const float* __restrict__ A1, const float* __restrict__ A2,
    const short* __restrict__ W1dfrag, const short* __restrict__ W2frag,
    const float* __restrict__ b2, float* __restrict__ out)
{
  int bid = blockIdx.x;
  int b = bid / 288;
  int rem = bid - b * 288;
  int tq = rem / 24, tk = rem - (rem / 24) * 24;
  int q0 = tq * 32, k0 = tk * 16;

  __shared__ __align__(16) char smem[62208];
  float* sK  = (float*)smem;               // [3][16][68] f32 = 13056 B
  short* sW2 = (short*)(smem + 13056);     // 16384 B (linear frag order)
  char*  hall = smem + 29440;              // 8 waves x 4096 B

  int tid = threadIdx.x;
  int w = tid >> 6, l = tid & 63;
  int g = l >> 4, r16 = l & 15;

  // ---- stage K equi tile into LDS (padded rows of 68) ----
  const float* ksrc = k_equi + ((size_t)(b * NK + k0)) * 192;
  #pragma unroll
  for (int it = 0; it < 6; ++it) {
    int j = tid + it * 512;
    int rr = j / 192, cd = j - rr * 192;
    int c = cd >> 6, d = cd & 63;
    sK[c * 1088 + rr * 68 + d] = ksrc[j];
  }
  // ---- stage W2 frags into LDS (linear copy) ----
  {
    short8 v0 = *(const short8*)&W2frag[tid * 8];
    short8 v1 = *(const short8*)&W2frag[(tid + 512) * 8];
    *(short8*)&sW2[tid * 8] = v0;
    *(short8*)&sW2[(tid + 512) * 8] = v1;
  }
  // ---- W1 frags into registers (kept live across whole kernel) ----
  short8 w1f[8][2];
  #pragma unroll
  for (int ft = 0; ft < 8; ++ft)
    #pragma unroll
    for (int s = 0; s < 2; ++s)
      w1f[ft][s] = *(const short8*)&W1dfrag[(((ft * 2 + s) * 64) + l) * 8];

  float4_ b2v[4];
  #pragma unroll
  for (int ot = 0; ot < 4; ++ot)
    b2v[ot] = *(const float4_*)&b2[ot * 16 + g * 4];

  __syncthreads();

  char* hbase = hall + w * 4096;
  const float* A1p = A1 + ((size_t)(b * NQ + q0)) * 128;
  const float* A2p = A2 + ((size_t)(b * NK + k0)) * 128;
  const float* qrow_base = q_equi + ((size_t)(b * NQ + q0)) * 192;

  #pragma unroll 1
  for (int qq = 0; qq < 4; ++qq) {
    int qi = w * 4 + qq;
    const float* qrow = qrow_base + (size_t)qi * 192;

    // ---- dot-product B-fragments: lane holds col ki=r16, k-elems d = s*32+g*8+i ----
    short8 afrag[2];
    #pragma unroll
    for (int s = 0; s < 2; ++s) {
      int d0 = s * 32 + g * 8;
      float da[4] = {0.f, 0.f, 0.f, 0.f};
      float db[4] = {0.f, 0.f, 0.f, 0.f};
      #pragma unroll
      for (int c = 0; c < 3; ++c) {
        float4_ kva = *(const float4_*)&sK[c * 1088 + r16 * 68 + d0];
        float4_ kvb = *(const float4_*)&sK[c * 1088 + r16 * 68 + d0 + 4];
        float4_ qva = *(const float4_*)&qrow[c * 64 + d0];
        float4_ qvb = *(const float4_*)&qrow[c * 64 + d0 + 4];
        #pragma unroll
        for (int i = 0; i < 4; ++i) {
          da[i] += qva[i] * kva[i];
          db[i] += qvb[i] * kvb[i];
        }
      }
      union { short8 s8; unsigned int u[4]; } au;
      au.u[0] = pk2(da[0], da[1]);
      au.u[1] = pk2(da[2], da[3]);
      au.u[2] = pk2(db[0], db[1]);
      au.u[3] = pk2(db[2], db[3]);
      afrag[s] = au.s8;
    }

    // ---- GEMM1': acc1[ft] = A1[qi][f] + A2[ki][f] + (W1dT x dot) ----
    float4_ acc1[8];
    #pragma unroll
    for (int ft = 0; ft < 8; ++ft) {
      float4_ a1v = *(const float4_*)&A1p[qi * 128 + ft * 16 + g * 4];
      float4_ a2v = *(const float4_*)&A2p[r16 * 128 + ft * 16 + g * 4];
      acc1[ft] = a1v + a2v;
    }
    #pragma unroll
    for (int ft = 0; ft < 8; ++ft)
      #pragma unroll
      for (int s = 0; s < 2; ++s)
        acc1[ft] = __builtin_amdgcn_mfma_f32_16x16x32_bf16(w1f[ft][s], afrag[s], acc1[ft], 0, 0, 0);

    // ---- silu -> packed bf16 -> wave-private LDS h[ki=r16][f] (XOR swizzled) ----
    #pragma unroll
    for (int ft = 0; ft < 8; ++ft) {
      float4_ x = acc1[ft];
      float y0 = x[0] / (1.f + __expf(-x[0]));
      float y1 = x[1] / (1.f + __expf(-x[1]));
      float y2 = x[2] / (1.f + __expf(-x[2]));
      float y3 = x[3] / (1.f + __expf(-x[3]));
      uint2_ pv;
      pv[0] = pk2(y0, y1);
      pv[1] = pk2(y2, y3);
      int byte = (r16 * 256 + ft * 32 + g * 8) ^ ((r16 & 7) << 4);
      *(uint2_*)(hbase + byte) = pv;
    }

    // ---- GEMM2': acc2 = b2 + W2T x hT ----
    float4_ acc2[4];
    #pragma unroll
    for (int ot = 0; ot < 4; ++ot) acc2[ot] = b2v[ot];
    #pragma unroll
    for (int s2 = 0; s2 < 4; ++s2) {
      int byte = (r16 * 256 + s2 * 64 + g * 16) ^ ((r16 & 7) << 4);
      short8 hb = *(const short8*)(hbase + byte);
      #pragma unroll
      for (int ot = 0; ot < 4; ++ot) {
        short8 wf = *(const short8*)&sW2[(((ot * 4 + s2) * 64) + l) * 8];
        acc2[ot] = __builtin_amdgcn_mfma_f32_16x16x32_bf16(wf, hb, acc2[ot], 0, 0, 0);
      }
    }

    // ---- store: rows o = ot*16+g*4+rr for pair (q0+qi, k0+r16) ----
    float* op = out + ((size_t)(b * NQ + q0 + qi) * NK + k0 + r16) * 64;
    #pragma unroll
    for (int ot = 0; ot < 4; ++ot)
      *(float4_*)(op + ot * 16 + g * 4) = acc2[ot];
  }
}

extern "C" void kernel_launch(void* const* d_in, const int* in_sizes, int n_in,
                              void* d_out, int out_size, void* d_ws, size_t ws_size,
                              hipStream_t stream) {
  (void)in_sizes; (void)n_in; (void)out_size; (void)ws_size;
  const float* q_equi = (const float*)d_in[0];
  const float* q_inv  = (const float*)d_in[1];
  const float* k_equi = (const float*)d_in[2];
  const float* k_inv  = (const float*)d_in[3];
  const float* Wq = (const float*)d_in[4];
  const float* bq = (const float*)d_in[5];
  const float* Wk = (const float*)d_in[6];
  const float* bk = (const float*)d_in[7];
  const float* W1 = (const float*)d_in[8];
  const float* b1 = (const float*)d_in[9];
  const float* W2 = (const float*)d_in[10];
  const float* b2 = (const float*)d_in[11];
  float* out = (float*)d_out;

  char* ws = (char*)d_ws;
  float* A1      = (float*)(ws);                // 786432 B
  float* A2      = (float*)(ws + 786432);       // 786432 B
  short* W1dfrag = (short*)(ws + 1572864);      // 16384 B
  short* W2frag  = (short*)(ws + 1589248);      // 16384 B
  float* Wqc     = (float*)(ws + 1605632);      // 131072 B
  float* Wkc     = (float*)(ws + 1736704);      // 131072 B
  float* c1      = (float*)(ws + 1867776);      // 512 B
  float* c2      = (float*)(ws + 1868288);      // 512 B

  prep0<<<34, 256, 0, stream>>>(Wq, Wk, W1, b1, bq, bk, W2, Wqc, Wkc, c1, c2, W1dfrag, W2frag);
  prep1<<<384, 256, 0, stream>>>(q_inv, k_inv, Wqc, Wkc, c1, c2, A1, A2);
  main_kernel<<<1152, 512, 0, stream>>>(q_equi, k_equi, A1, A2, W1dfrag, W2frag, b2, out);
}

// Round 5
// 261.528 us; speedup vs baseline: 1.2203x; 1.2203x over previous
//
#include <hip/hip_runtime.h>
#include <hip/hip_bf16.h>
#include <stdint.h>
#include <stddef.h>

#define NQ 384
#define NK 384

typedef __attribute__((ext_vector_type(4))) float float4_;
typedef __attribute__((ext_vector_type(8))) short short8;
typedef __attribute__((ext_vector_type(2))) unsigned int uint2_;

__device__ __forceinline__ short f2bf(float f) {
  union { float f; uint32_t u; } v; v.f = f;
  uint32_t u = v.u;
  uint32_t r = (u + 0x7fffu + ((u >> 16) & 1u)) >> 16;
  return (short)r;
}

__device__ __forceinline__ unsigned int pk2(float lo, float hi) {
  __hip_bfloat162 r = __float22bfloat162_rn(make_float2(lo, hi));
  union { __hip_bfloat162 b; unsigned int u; } u; u.b = r;
  return u.u;
}

// ---------------- prep0: weight combine + bias combine + frag pack ----------------
__global__ __launch_bounds__(256) void prep0(
    const float* __restrict__ Wq, const float* __restrict__ Wk,
    const float* __restrict__ W1, const float* __restrict__ b1,
    const float* __restrict__ bq, const float* __restrict__ bk,
    const float* __restrict__ W2,
    float* __restrict__ Wqc, float* __restrict__ Wkc,
    float* __restrict__ c1, float* __restrict__ c2,
    short* __restrict__ W1dfrag, short* __restrict__ W2frag)
{
  int bid = blockIdx.x, t = threadIdx.x;
  if (bid < 32) {
    int side = bid >> 4;
    int r0 = (bid & 15) * 16;
    const float* W = side ? Wk : Wq;
    const float* W1s = W1 + side * 64 * 128;
    float* Wc = side ? Wkc : Wqc;
    __shared__ float sW[16][64];
    for (int j = t; j < 1024; j += 256) sW[j >> 6][j & 63] = W[(r0 + (j >> 6)) * 64 + (j & 63)];
    __syncthreads();
    int c = t & 127, rg = (t >> 7) * 8;
    float acc[8] = {0.f, 0.f, 0.f, 0.f, 0.f, 0.f, 0.f, 0.f};
    for (int k = 0; k < 64; ++k) {
      float wv = W1s[k * 128 + c];
      #pragma unroll
      for (int j = 0; j < 8; ++j) acc[j] += sW[rg + j][k] * wv;
    }
    for (int j = 0; j < 8; ++j) Wc[(r0 + rg + j) * 128 + c] = acc[j];
  } else if (bid == 32) {
    if (t < 256) {
      int c = t & 127, side = t >> 7;
      const float* bias = side ? bk : bq;
      const float* W1s = W1 + side * 64 * 128;
      float acc = side ? 0.f : b1[c];
      for (int k = 0; k < 64; ++k) acc += bias[k] * W1s[k * 128 + c];
      (side ? c2 : c1)[c] = acc;
    }
  } else {
    for (int idx = t; idx < 8192; idx += 256) {
      int fi = idx >> 9;
      int l  = (idx >> 3) & 63;
      int i  = idx & 7;
      { int n = fi >> 1, s = fi & 1;
        int d = s * 32 + ((l >> 4) << 3) + i;
        int f = n * 16 + (l & 15);
        W1dfrag[idx] = f2bf(W1[(128 + d) * 128 + f]); }
      { int n2 = fi >> 2, s2 = fi & 3;
        int k = s2 * 32 + ((l >> 4) << 3) + i;
        int o = n2 * 16 + (l & 15);
        W2frag[idx] = f2bf(W2[k * 64 + o]); }
    }
  }
}

// ---------------- prep1: A1 = q_inv@Wqc + c1 ; A2 = k_inv@Wkc + c2 ----------------
__global__ __launch_bounds__(256) void prep1(
    const float* __restrict__ q_inv, const float* __restrict__ k_inv,
    const float* __restrict__ Wqc, const float* __restrict__ Wkc,
    const float* __restrict__ c1, const float* __restrict__ c2,
    float* __restrict__ A1, float* __restrict__ A2)
{
  int bid = blockIdx.x, t = threadIdx.x;
  int row0 = bid * 8;
  int side = row0 >= 1536;
  int r0 = row0 - side * 1536;
  const float* inv = (side ? k_inv : q_inv) + (size_t)r0 * 256;
  const float* Wc  = side ? Wkc : Wqc;
  const float* cc  = side ? c2 : c1;
  float* A = (side ? A2 : A1) + (size_t)r0 * 128;

  __shared__ float sI[8][256];
  for (int j = t; j < 2048; j += 256) sI[j >> 8][j & 255] = inv[j];
  __syncthreads();

  int c = t & 127, rg = (t >> 7) * 4;
  float acc[4] = {0.f, 0.f, 0.f, 0.f};
  for (int k = 0; k < 256; ++k) {
    float wv = Wc[k * 128 + c];
    #pragma unroll
    for (int j = 0; j < 4; ++j) acc[j] += sI[rg + j][k] * wv;
  }
  float cv = cc[c];
  #pragma unroll
  for (int j = 0; j < 4; ++j) A[(size_t)(rg + j) * 128 + c] = acc[j] + cv;
}

// ---------------- main fused kernel ----------------
// block = (b, 16 q, 16 k); 8 waves; wave w owns qi in {2w, 2w+1} (m-paired ILP).
// Swapped-operand GEMMs: GEMM1' hT = W1dT x DotT ; GEMM2' outT = W2T x hT.
// LDS: sK (13 KB) overlaid by 8x4KB wave-private h after barrier 2. Q from global.
__global__ __launch_bounds__(512) void main_kernel(
    const float* __restrict__ q_equi, const float* __restrict__ k_equi,
    const float* __restrict__ A1, const float* __restrict__ A2,
    const short* __restrict__ W1dfrag, const short* __restrict__ W2frag,
    const float* __restrict__ b2, float* __restrict__ out)
{
  int bid0 = blockIdx.x;
  int bid = (bid0 & 7) * 288 + (bid0 >> 3);   // XCD-contiguous panels (2304 % 8 == 0)
  int b = bid / 576;
  int rem = bid - b * 576;
  int tq = rem / 24, tk = rem - (rem / 24) * 24;
  int q0 = tq * 16, k0 = tk * 16;

  __shared__ __align__(16) char smem[32768];
  float* sK = (float*)smem;           // [3][16][68] f32 = 13056 B (phase 1)
  // phase 2: wave w's h tile at smem + w*4096 : [16 ki][128 f] bf16, XOR swizzled

  int tid = threadIdx.x;
  int w = tid >> 6, l = tid & 63;
  int g = l >> 4, r16 = l & 15;

  // ---- stage K equi tile (padded rows of 68) ----
  const float* ksrc = k_equi + ((size_t)(b * NK + k0)) * 192;
  #pragma unroll
  for (int it = 0; it < 6; ++it) {
    int j = tid + it * 512;
    int rr = j / 192, cd = j - rr * 192;
    int c = cd >> 6, d = cd & 63;
    sK[c * 1088 + rr * 68 + d] = ksrc[j];
  }
  __syncthreads();

  // ---- dot-product B-fragments (lane: col ki=r16, k-elems d = s*32+g*8+i) ----
  const float* qrow0 = q_equi + ((size_t)(b * NQ + q0 + 2 * w)) * 192;
  short8 afrag[2][2];
  #pragma unroll
  for (int s = 0; s < 2; ++s) {
    int d0 = s * 32 + g * 8;
    float4_ kva[3], kvb[3];
    #pragma unroll
    for (int c = 0; c < 3; ++c) {
      kva[c] = *(const float4_*)&sK[c * 1088 + r16 * 68 + d0];
      kvb[c] = *(const float4_*)&sK[c * 1088 + r16 * 68 + d0 + 4];
    }
    #pragma unroll
    for (int m = 0; m < 2; ++m) {
      const float* qrow = qrow0 + m * 192;
      float da[4] = {0.f, 0.f, 0.f, 0.f};
      float db[4] = {0.f, 0.f, 0.f, 0.f};
      #pragma unroll
      for (int c = 0; c < 3; ++c) {
        float4_ qva = *(const float4_*)&qrow[c * 64 + d0];
        float4_ qvb = *(const float4_*)&qrow[c * 64 + d0 + 4];
        #pragma unroll
        for (int i = 0; i < 4; ++i) {
          da[i] += qva[i] * kva[c][i];
          db[i] += qvb[i] * kvb[c][i];
        }
      }
      union { short8 s8; unsigned int u[4]; } au;
      au.u[0] = pk2(da[0], da[1]);
      au.u[1] = pk2(da[2], da[3]);
      au.u[2] = pk2(db[0], db[1]);
      au.u[3] = pk2(db[2], db[3]);
      afrag[m][s] = au.s8;
    }
  }
  __syncthreads();   // all sK reads done; smem becomes wave-private h tiles

  // ---- acc1 init: A1[qi][f] + A2[ki][f], float4, A2 shared across m ----
  const float* A1p = A1 + ((size_t)(b * NQ + q0 + 2 * w)) * 128;
  const float* A2p = A2 + ((size_t)(b * NK + k0)) * 128;
  float4_ acc1[2][8];
  #pragma unroll
  for (int ft = 0; ft < 8; ++ft) {
    float4_ a2v = *(const float4_*)&A2p[r16 * 128 + ft * 16 + g * 4];
    acc1[0][ft] = *(const float4_*)&A1p[ft * 16 + g * 4] + a2v;
    acc1[1][ft] = *(const float4_*)&A1p[128 + ft * 16 + g * 4] + a2v;
  }

  // ---- GEMM1': weight frag loaded once per (ft,s), both m consume ----
  #pragma unroll
  for (int ft = 0; ft < 8; ++ft) {
    #pragma unroll
    for (int s = 0; s < 2; ++s) {
      short8 wf = *(const short8*)&W1dfrag[(((ft * 2 + s) * 64) + l) * 8];
      #pragma unroll
      for (int m = 0; m < 2; ++m)
        acc1[m][ft] = __builtin_amdgcn_mfma_f32_16x16x32_bf16(wf, afrag[m][s], acc1[m][ft], 0, 0, 0);
    }
  }

  // ---- silu -> h LDS (reused buffer) -> GEMM2 B-frags into regs, per m ----
  char* hbase = smem + w * 4096;
  short8 hb[2][4];
  #pragma unroll
  for (int m = 0; m < 2; ++m) {
    #pragma unroll
    for (int ft = 0; ft < 8; ++ft) {
      float4_ x = acc1[m][ft];
      float y0 = x[0] / (1.f + __expf(-x[0]));
      float y1 = x[1] / (1.f + __expf(-x[1]));
      float y2 = x[2] / (1.f + __expf(-x[2]));
      float y3 = x[3] / (1.f + __expf(-x[3]));
      uint2_ pv;
      pv[0] = pk2(y0, y1);
      pv[1] = pk2(y2, y3);
      int byte = (r16 * 256 + ft * 32 + g * 8) ^ ((r16 & 7) << 4);
      *(uint2_*)(hbase + byte) = pv;
    }
    #pragma unroll
    for (int s2 = 0; s2 < 4; ++s2) {
      int byte = (r16 * 256 + s2 * 64 + g * 16) ^ ((r16 & 7) << 4);
      hb[m][s2] = *(const short8*)(hbase + byte);   // DS in-order per wave: reads see this m's writes
    }
  }

  // ---- GEMM2': weight frag loaded once per (ot,s2), both m consume ----
  float4_ b2v[4];
  #pragma unroll
  for (int ot = 0; ot < 4; ++ot)
    b2v[ot] = *(const float4_*)&b2[ot * 16 + g * 4];
  float4_ acc2[2][4];
  #pragma unroll
  for (int m = 0; m < 2; ++m)
    #pragma unroll
    for (int ot = 0; ot < 4; ++ot) acc2[m][ot] = b2v[ot];
  #pragma unroll
  for (int s2 = 0; s2 < 4; ++s2) {
    #pragma unroll
    for (int ot = 0; ot < 4; ++ot) {
      short8 wf = *(const short8*)&W2frag[(((ot * 4 + s2) * 64) + l) * 8];
      #pragma unroll
      for (int m = 0; m < 2; ++m)
        acc2[m][ot] = __builtin_amdgcn_mfma_f32_16x16x32_bf16(wf, hb[m][s2], acc2[m][ot], 0, 0, 0);
    }
  }

  // ---- epilogue: float4 stores, rows o = ot*16+g*4+rr, pair (q0+2w+m, k0+r16) ----
  #pragma unroll
  for (int m = 0; m < 2; ++m) {
    float* op = out + ((size_t)(b * NQ + q0 + 2 * w + m) * NK + k0 + r16) * 64;
    #pragma unroll
    for (int ot = 0; ot < 4; ++ot)
      *(float4_*)(op + ot * 16 + g * 4) = acc2[m][ot];
  }
}

extern "C" void kernel_launch(void* const* d_in, const int* in_sizes, int n_in,
                              void* d_out, int out_size, void* d_ws, size_t ws_size,
                              hipStream_t stream) {
  (void)in_sizes; (void)n_in; (void)out_size; (void)ws_size;
  const float* q_equi = (const float*)d_in[0];
  const float* q_inv  = (const float*)d_in[1];
  const float* k_equi = (const float*)d_in[2];
  const float* k_inv  = (const float*)d_in[3];
  const float* Wq = (const float*)d_in[4];
  const float* bq = (const float*)d_in[5];
  const float* Wk = (const float*)d_in[6];
  const float* bk = (const float*)d_in[7];
  const float* W1 = (const float*)d_in[8];
  const float* b1 = (const float*)d_in[9];
  const float* W2 = (const float*)d_in[10];
  const float* b2 = (const float*)d_in[11];
  float* out = (float*)d_out;

  char* ws = (char*)d_ws;
  float* A1      = (float*)(ws);                // 786432 B
  float* A2      = (float*)(ws + 786432);       // 786432 B
  short* W1dfrag = (short*)(ws + 1572864);      // 16384 B
  short* W2frag  = (short*)(ws + 1589248);      // 16384 B
  float* Wqc     = (float*)(ws + 1605632);      // 131072 B
  float* Wkc     = (float*)(ws + 1736704);      // 131072 B
  float* c1      = (float*)(ws + 1867776);      // 512 B
  float* c2      = (float*)(ws + 1868288);      // 512 B

  prep0<<<34, 256, 0, stream>>>(Wq, Wk, W1, b1, bq, bk, W2, Wqc, Wkc, c1, c2, W1dfrag, W2frag);
  prep1<<<384, 256, 0, stream>>>(q_inv, k_inv, Wqc, Wkc, c1, c2, A1, A2);
  main_kernel<<<2304, 512, 0, stream>>>(q_equi, k_equi, A1, A2, W1dfrag, W2frag, b2, out);
}

// Round 6
// 253.706 us; speedup vs baseline: 1.2579x; 1.0308x over previous
//
#include <hip/hip_runtime.h>
#include <hip/hip_bf16.h>
#include <stdint.h>
#include <stddef.h>

#define NQ 384
#define NK 384

typedef __attribute__((ext_vector_type(4))) float float4_;
typedef __attribute__((ext_vector_type(8))) short short8;
typedef __attribute__((ext_vector_type(2))) unsigned int uint2_;

__device__ __forceinline__ short f2bf(float f) {
  union { float f; uint32_t u; } v; v.f = f;
  uint32_t u = v.u;
  uint32_t r = (u + 0x7fffu + ((u >> 16) & 1u)) >> 16;
  return (short)r;
}

__device__ __forceinline__ unsigned int pk2(float lo, float hi) {
  __hip_bfloat162 r = __float22bfloat162_rn(make_float2(lo, hi));
  union { __hip_bfloat162 b; unsigned int u; } u; u.b = r;
  return u.u;
}

// ---------------- prep0: weight combine + bias combine + frag pack ----------------
__global__ __launch_bounds__(256) void prep0(
    const float* __restrict__ Wq, const float* __restrict__ Wk,
    const float* __restrict__ W1, const float* __restrict__ b1,
    const float* __restrict__ bq, const float* __restrict__ bk,
    const float* __restrict__ W2,
    float* __restrict__ Wqc, float* __restrict__ Wkc,
    float* __restrict__ c1, float* __restrict__ c2,
    short* __restrict__ W1dfrag, short* __restrict__ W2frag)
{
  int bid = blockIdx.x, t = threadIdx.x;
  if (bid < 32) {
    int side = bid >> 4;
    int r0 = (bid & 15) * 16;
    const float* W = side ? Wk : Wq;
    const float* W1s = W1 + side * 64 * 128;
    float* Wc = side ? Wkc : Wqc;
    __shared__ float sW[16][64];
    for (int j = t; j < 1024; j += 256) sW[j >> 6][j & 63] = W[(r0 + (j >> 6)) * 64 + (j & 63)];
    __syncthreads();
    int c = t & 127, rg = (t >> 7) * 8;
    float acc[8] = {0.f, 0.f, 0.f, 0.f, 0.f, 0.f, 0.f, 0.f};
    for (int k = 0; k < 64; ++k) {
      float wv = W1s[k * 128 + c];
      #pragma unroll
      for (int j = 0; j < 8; ++j) acc[j] += sW[rg + j][k] * wv;
    }
    for (int j = 0; j < 8; ++j) Wc[(r0 + rg + j) * 128 + c] = acc[j];
  } else if (bid == 32) {
    if (t < 256) {
      int c = t & 127, side = t >> 7;
      const float* bias = side ? bk : bq;
      const float* W1s = W1 + side * 64 * 128;
      float acc = side ? 0.f : b1[c];
      for (int k = 0; k < 64; ++k) acc += bias[k] * W1s[k * 128 + c];
      (side ? c2 : c1)[c] = acc;
    }
  } else {
    for (int idx = t; idx < 8192; idx += 256) {
      int fi = idx >> 9;
      int l  = (idx >> 3) & 63;
      int i  = idx & 7;
      { int n = fi >> 1, s = fi & 1;
        int d = s * 32 + ((l >> 4) << 3) + i;
        int f = n * 16 + (l & 15);
        W1dfrag[idx] = f2bf(W1[(128 + d) * 128 + f]); }
      { int n2 = fi >> 2, s2 = fi & 3;
        int k = s2 * 32 + ((l >> 4) << 3) + i;
        int o = n2 * 16 + (l & 15);
        W2frag[idx] = f2bf(W2[k * 64 + o]); }
    }
  }
}

// ---------------- prep1: A1 = q_inv@Wqc + c1 ; A2 = k_inv@Wkc + c2 ----------------
__global__ __launch_bounds__(256) void prep1(
    const float* __restrict__ q_inv, const float* __restrict__ k_inv,
    const float* __restrict__ Wqc, const float* __restrict__ Wkc,
    const float* __restrict__ c1, const float* __restrict__ c2,
    float* __restrict__ A1, float* __restrict__ A2)
{
  int bid = blockIdx.x, t = threadIdx.x;
  int row0 = bid * 8;
  int side = row0 >= 1536;
  int r0 = row0 - side * 1536;
  const float* inv = (side ? k_inv : q_inv) + (size_t)r0 * 256;
  const float* Wc  = side ? Wkc : Wqc;
  const float* cc  = side ? c2 : c1;
  float* A = (side ? A2 : A1) + (size_t)r0 * 128;

  __shared__ float sI[8][256];
  for (int j = t; j < 2048; j += 256) sI[j >> 8][j & 255] = inv[j];
  __syncthreads();

  int c = t & 127, rg = (t >> 7) * 4;
  float acc[4] = {0.f, 0.f, 0.f, 0.f};
  for (int k = 0; k < 256; ++k) {
    float wv = Wc[k * 128 + c];
    #pragma unroll
    for (int j = 0; j < 4; ++j) acc[j] += sI[rg + j][k] * wv;
  }
  float cv = cc[c];
  #pragma unroll
  for (int j = 0; j < 4; ++j) A[(size_t)(rg + j) * 128 + c] = acc[j] + cv;
}

// ---------------- main fused kernel ----------------
// block = (b, 16 q, 16 k); 8 waves; wave w owns qi in {2w, 2w+1} (m-paired ILP).
// K tile staged via global_load_lds (16B, bank-XOR pre-swizzled source, linear LDS).
// Swapped-operand GEMMs; h wave-private LDS (overlays sK after barrier 2).
__global__ __launch_bounds__(512) void main_kernel(
    const float* __restrict__ q_equi, const float* __restrict__ k_equi,
    const float* __restrict__ A1, const float* __restrict__ A2,
    const short* __restrict__ W1dfrag, const short* __restrict__ W2frag,
    const float* __restrict__ b2, float* __restrict__ out)
{
  int bid = blockIdx.x;
  int b = bid / 576;
  int rem = bid - b * 576;
  int tq = rem / 24, tk = rem - (rem / 24) * 24;
  int q0 = tq * 16, k0 = tk * 16;

  __shared__ __align__(16) char smem[32768];
  float* sK = (float*)smem;   // [16 rows][48 units of 16B], unit jj holds global unit jj^(r&7)
  // phase 2: wave w's h tile at smem + w*4096 : [16 ki][128 f] bf16, XOR swizzled

  int tid = threadIdx.x;
  int w = tid >> 6, l = tid & 63;
  int g = l >> 4, r16 = l & 15;

  // ---- stage K equi tile: 768 x 16B units, direct global->LDS ----
  // LDS unit u = r*48 + jj  <-  global unit (r, jj ^ (r&7))
  const float* ksrc = k_equi + ((size_t)(b * NK + k0)) * 192;
  {
    int u = tid;
    int r = u / 48, jj = u - r * 48;
    int j = jj ^ (r & 7);
    __builtin_amdgcn_global_load_lds(ksrc + r * 192 + j * 4, smem + u * 16, 16, 0, 0);
    if (tid < 256) {
      int u2 = tid + 512;
      int r2 = u2 / 48, jj2 = u2 - r2 * 48;
      int j2 = jj2 ^ (r2 & 7);
      __builtin_amdgcn_global_load_lds(ksrc + r2 * 192 + j2 * 4, smem + u2 * 16, 16, 0, 0);
    }
  }
  __syncthreads();

  // ---- dot-product B-fragments (lane: col ki=r16, k-elems d = s*32+g*8+i) ----
  const float* qrow0 = q_equi + ((size_t)(b * NQ + q0 + 2 * w)) * 192;
  const float* krow = sK + r16 * 48 * 4;
  int x7 = r16 & 7;
  short8 afrag[2][2];
  #pragma unroll
  for (int s = 0; s < 2; ++s) {
    int d0 = s * 32 + g * 8;
    float4_ kva[3], kvb[3];
    #pragma unroll
    for (int c = 0; c < 3; ++c) {
      int j0 = c * 16 + s * 8 + g * 2;
      kva[c] = *(const float4_*)&krow[((j0) ^ x7) * 4];
      kvb[c] = *(const float4_*)&krow[((j0 + 1) ^ x7) * 4];
    }
    #pragma unroll
    for (int m = 0; m < 2; ++m) {
      const float* qrow = qrow0 + m * 192;
      float da[4] = {0.f, 0.f, 0.f, 0.f};
      float db[4] = {0.f, 0.f, 0.f, 0.f};
      #pragma unroll
      for (int c = 0; c < 3; ++c) {
        float4_ qva = *(const float4_*)&qrow[c * 64 + d0];
        float4_ qvb = *(const float4_*)&qrow[c * 64 + d0 + 4];
        #pragma unroll
        for (int i = 0; i < 4; ++i) {
          da[i] += qva[i] * kva[c][i];
          db[i] += qvb[i] * kvb[c][i];
        }
      }
      union { short8 s8; unsigned int u[4]; } au;
      au.u[0] = pk2(da[0], da[1]);
      au.u[1] = pk2(da[2], da[3]);
      au.u[2] = pk2(db[0], db[1]);
      au.u[3] = pk2(db[2], db[3]);
      afrag[m][s] = au.s8;
    }
  }
  __syncthreads();   // all sK reads done; smem becomes wave-private h tiles

  // ---- acc1 init: A1[qi][f] + A2[ki][f], float4, A2 shared across m ----
  const float* A1p = A1 + ((size_t)(b * NQ + q0 + 2 * w)) * 128;
  const float* A2p = A2 + ((size_t)(b * NK + k0)) * 128;
  float4_ acc1[2][8];
  #pragma unroll
  for (int ft = 0; ft < 8; ++ft) {
    float4_ a2v = *(const float4_*)&A2p[r16 * 128 + ft * 16 + g * 4];
    acc1[0][ft] = *(const float4_*)&A1p[ft * 16 + g * 4] + a2v;
    acc1[1][ft] = *(const float4_*)&A1p[128 + ft * 16 + g * 4] + a2v;
  }

  // ---- GEMM1': weight frag loaded once per (ft,s), both m consume ----
  #pragma unroll
  for (int ft = 0; ft < 8; ++ft) {
    #pragma unroll
    for (int s = 0; s < 2; ++s) {
      short8 wf = *(const short8*)&W1dfrag[(((ft * 2 + s) * 64) + l) * 8];
      #pragma unroll
      for (int m = 0; m < 2; ++m)
        acc1[m][ft] = __builtin_amdgcn_mfma_f32_16x16x32_bf16(wf, afrag[m][s], acc1[m][ft], 0, 0, 0);
    }
  }

  // ---- fast silu -> h LDS (reused buffer) -> GEMM2 B-frags into regs, per m ----
  char* hbase = smem + w * 4096;
  short8 hb[2][4];
  #pragma unroll
  for (int m = 0; m < 2; ++m) {
    #pragma unroll
    for (int ft = 0; ft < 8; ++ft) {
      float4_ x = acc1[m][ft];
      float y0 = x[0] * __builtin_amdgcn_rcpf(1.f + __expf(-x[0]));
      float y1 = x[1] * __builtin_amdgcn_rcpf(1.f + __expf(-x[1]));
      float y2 = x[2] * __builtin_amdgcn_rcpf(1.f + __expf(-x[2]));
      float y3 = x[3] * __builtin_amdgcn_rcpf(1.f + __expf(-x[3]));
      uint2_ pv;
      pv[0] = pk2(y0, y1);
      pv[1] = pk2(y2, y3);
      int byte = (r16 * 256 + ft * 32 + g * 8) ^ ((r16 & 7) << 4);
      *(uint2_*)(hbase + byte) = pv;
    }
    #pragma unroll
    for (int s2 = 0; s2 < 4; ++s2) {
      int byte = (r16 * 256 + s2 * 64 + g * 16) ^ ((r16 & 7) << 4);
      hb[m][s2] = *(const short8*)(hbase + byte);   // DS in-order per wave
    }
  }

  // ---- GEMM2': weight frag loaded once per (ot,s2), both m consume ----
  float4_ b2v[4];
  #pragma unroll
  for (int ot = 0; ot < 4; ++ot)
    b2v[ot] = *(const float4_*)&b2[ot * 16 + g * 4];
  float4_ acc2[2][4];
  #pragma unroll
  for (int m = 0; m < 2; ++m)
    #pragma unroll
    for (int ot = 0; ot < 4; ++ot) acc2[m][ot] = b2v[ot];
  #pragma unroll
  for (int s2 = 0; s2 < 4; ++s2) {
    #pragma unroll
    for (int ot = 0; ot < 4; ++ot) {
      short8 wf = *(const short8*)&W2frag[(((ot * 4 + s2) * 64) + l) * 8];
      #pragma unroll
      for (int m = 0; m < 2; ++m)
        acc2[m][ot] = __builtin_amdgcn_mfma_f32_16x16x32_bf16(wf, hb[m][s2], acc2[m][ot], 0, 0, 0);
    }
  }

  // ---- epilogue: float4 stores, rows o = ot*16+g*4+rr, pair (q0+2w+m, k0+r16) ----
  #pragma unroll
  for (int m = 0; m < 2; ++m) {
    float* op = out + ((size_t)(b * NQ + q0 + 2 * w + m) * NK + k0 + r16) * 64;
    #pragma unroll
    for (int ot = 0; ot < 4; ++ot)
      *(float4_*)(op + ot * 16 + g * 4) = acc2[m][ot];
  }
}

extern "C" void kernel_launch(void* const* d_in, const int* in_sizes, int n_in,
                              void* d_out, int out_size, void* d_ws, size_t ws_size,
                              hipStream_t stream) {
  (void)in_sizes; (void)n_in; (void)out_size; (void)ws_size;
  const float* q_equi = (const float*)d_in[0];
  const float* q_inv  = (const float*)d_in[1];
  const float* k_equi = (const float*)d_in[2];
  const float* k_inv  = (const float*)d_in[3];
  const float* Wq = (const float*)d_in[4];
  const float* bq = (const float*)d_in[5];
  const float* Wk = (const float*)d_in[6];
  const float* bk = (const float*)d_in[7];
  const float* W1 = (const float*)d_in[8];
  const float* b1 = (const float*)d_in[9];
  const float* W2 = (const float*)d_in[10];
  const float* b2 = (const float*)d_in[11];
  float* out = (float*)d_out;

  char* ws = (char*)d_ws;
  float* A1      = (float*)(ws);                // 786432 B
  float* A2      = (float*)(ws + 786432);       // 786432 B
  short* W1dfrag = (short*)(ws + 1572864);      // 16384 B
  short* W2frag  = (short*)(ws + 1589248);      // 16384 B
  float* Wqc     = (float*)(ws + 1605632);      // 131072 B
  float* Wkc     = (float*)(ws + 1736704);      // 131072 B
  float* c1      = (float*)(ws + 1867776);      // 512 B
  float* c2      = (float*)(ws + 1868288);      // 512 B

  prep0<<<34, 256, 0, stream>>>(Wq, Wk, W1, b1, bq, bk, W2, Wqc, Wkc, c1, c2, W1dfrag, W2frag);
  prep1<<<384, 256, 0, stream>>>(q_inv, k_inv, Wqc, Wkc, c1, c2, A1, A2);
  main_kernel<<<2304, 512, 0, stream>>>(q_equi, k_equi, A1, A2, W1dfrag, W2frag, b2, out);
}